// Round 1
// baseline (21538.980 us; speedup 1.0000x reference)
//
#include <hip/hip_runtime.h>
#include <hip/hip_bf16.h>
#include <hip/hip_cooperative_groups.h>

namespace cg = cooperative_groups;

typedef __attribute__((ext_vector_type(8))) short short8;
typedef __attribute__((ext_vector_type(4))) float f32x4;

static constexpr int E_ = 512, H_ = 1024, S_ = 512, B_ = 64, NT_ = 13, DFF_ = 256;
static constexpr int G4H = 4 * H_;  // 4096

// ---- workspace layout (bytes) ----
static constexpr size_t WIH_ELEMS = (size_t)NT_ * G4H * E_;   // 27,262,976 bf16
static constexpr size_t WHH_ELEMS = (size_t)NT_ * G4H * H_;   // 54,525,952 bf16
static constexpr size_t X_ELEMS   = (size_t)S_ * B_ * E_;     // 16,777,216 bf16
static constexpr size_t BIAS_ELEMS = (size_t)NT_ * G4H;       // 53,248 f32
static constexpr size_t HBUF_ELEMS = (size_t)B_ * H_;         // 65,536 (x2 buffers)

static constexpr size_t OFF_WIH  = 0;
static constexpr size_t OFF_WHH  = OFF_WIH + WIH_ELEMS * 2;
static constexpr size_t OFF_X    = OFF_WHH + WHH_ELEMS * 2;
static constexpr size_t OFF_BIAS = OFF_X + X_ELEMS * 2;
static constexpr size_t OFF_H    = OFF_BIAS + BIAS_ELEMS * 4;
static constexpr size_t OFF_HF   = OFF_H + 2 * HBUF_ELEMS * 2;
// total = OFF_HF + 65536*4 = 197,869,568 bytes (~189 MiB)

__device__ inline short f2bf(float x) {
  __hip_bfloat16 h = __float2bfloat16(x);
  return __builtin_bit_cast(short, h);
}

__device__ inline short8 cvt8(const float* src) {
  f32x4 a = *(const f32x4*)src;
  f32x4 b = *(const f32x4*)(src + 4);
  short8 o;
  o[0] = f2bf(a[0]); o[1] = f2bf(a[1]); o[2] = f2bf(a[2]); o[3] = f2bf(a[3]);
  o[4] = f2bf(b[0]); o[5] = f2bf(b[1]); o[6] = f2bf(b[2]); o[7] = f2bf(b[3]);
  return o;
}

__device__ inline float sigm(float x) { return 1.f / (1.f + __expf(-x)); }

// packed row p (within a tag) -> original row r:
//   p = wg16*16 + g*4 + u  maps to  r = g*1024 + wg16*4 + u
__device__ inline int unpack_row(int p) {
  return ((p >> 2) & 3) * H_ + (p >> 4) * 4 + (p & 3);
}

__global__ __launch_bounds__(256, 1) void lstm_tag_kernel(
    const int* __restrict__ tokens, const int* __restrict__ tags,
    const float* __restrict__ emb_w,
    const float* __restrict__ W_ih, const float* __restrict__ W_hh,
    const float* __restrict__ b_ih, const float* __restrict__ b_hh,
    const float* __restrict__ W1, const float* __restrict__ b1,
    const float* __restrict__ W2, const float* __restrict__ b2,
    float* __restrict__ out,
    short* __restrict__ wih_pk, short* __restrict__ whh_pk,
    short* __restrict__ x_bf, float* __restrict__ bias_pk,
    short* __restrict__ h_bf, float* __restrict__ h_f32) {
  cg::grid_group grid = cg::this_grid();
  const int tid = threadIdx.x;
  const int wg = blockIdx.x;        // 0..255
  const int lane = tid & 63;
  const int ll = tid >> 6;          // wave in WG, 0..3
  const int gw = wg * 4 + ll;       // global wave id 0..1023
  const int gtid = wg * 256 + tid;  // 0..65535

  // ================= Phase 0: pre-pass =================
  // Pack W_ih -> bf16, gate-interleaved rows. Each wave does one row (512 wide).
  for (int row = gw; row < NT_ * G4H; row += 1024) {
    int tag = row >> 12;
    int p = row & 4095;
    int r = unpack_row(p);
    const float* src = W_ih + ((size_t)tag * G4H + r) * E_ + lane * 8;
    short* dst = wih_pk + ((size_t)tag * G4H + p) * E_ + lane * 8;
    *(short8*)dst = cvt8(src);
  }
  // Pack W_hh (1024 wide: two chunks per lane).
  for (int row = gw; row < NT_ * G4H; row += 1024) {
    int tag = row >> 12;
    int p = row & 4095;
    int r = unpack_row(p);
    const float* src = W_hh + ((size_t)tag * G4H + r) * H_;
    short* dst = whh_pk + ((size_t)tag * G4H + p) * H_;
    *(short8*)(dst + lane * 8) = cvt8(src + lane * 8);
    *(short8*)(dst + 512 + lane * 8) = cvt8(src + 512 + lane * 8);
  }
  // Bias (packed order), per-thread.
  for (int idx = gtid; idx < NT_ * G4H; idx += 65536) {
    int tag = idx >> 12;
    int r = unpack_row(idx & 4095);
    bias_pk[idx] = b_ih[tag * G4H + r] + b_hh[tag * G4H + r];
  }
  // Embedding gather -> bf16, layout [t][b][e].
  for (int row = gw; row < S_ * B_; row += 1024) {
    int t = row >> 6, b = row & 63;
    int tok = tokens[b * S_ + t];
    const float* src = emb_w + (size_t)tok * E_ + lane * 8;
    short* dst = x_bf + (size_t)row * E_ + lane * 8;
    *(short8*)dst = cvt8(src);
  }
  // Zero both h buffers: 131072 shorts = 65536 ints, one per thread.
  ((int*)h_bf)[gtid] = 0;

  grid.sync();

  // ================= Phase 1: recurrence =================
  // WG wg owns hidden units j = wg*4 .. wg*4+3 (16 packed gate cols).
  // Wave ll owns batches m0..m0+15. Lane holds c for one (batch, hidden) pair.
  const int arow = lane & 15;       // A row within tile / B packed-col
  const int kq = (lane >> 4) * 8;   // k offset of this lane's fragment
  const int m0 = ll * 16;

  __shared__ float lds_tile[4 * 256];
  float* tl = lds_tile + ll * 256;

  float c_reg = 0.f;

  for (int t = 0; t < S_; ++t) {
    const int tag = tags[t];
    const short* A1 = x_bf + (size_t)t * B_ * E_;
    const short* Acur = h_bf + (size_t)(t & 1) * HBUF_ELEMS;
    short* Anext = h_bf + (size_t)((t + 1) & 1) * HBUF_ELEMS;
    const short* Bp1 = wih_pk + ((size_t)tag * G4H + wg * 16) * E_;
    const short* Bp2 = whh_pk + ((size_t)tag * G4H + wg * 16) * H_;

    f32x4 acc = {0.f, 0.f, 0.f, 0.f};
    {
      const short* ap = A1 + (m0 + arow) * E_ + kq;
      const short* bp = Bp1 + arow * E_ + kq;
#pragma unroll
      for (int kk = 0; kk < E_ / 32; ++kk) {
        short8 av = *(const short8*)(ap + kk * 32);
        short8 bv = *(const short8*)(bp + kk * 32);
        acc = __builtin_amdgcn_mfma_f32_16x16x32_bf16(av, bv, acc, 0, 0, 0);
      }
    }
    {
      const short* ap = Acur + (m0 + arow) * H_ + kq;
      const short* bp = Bp2 + arow * H_ + kq;
#pragma unroll
      for (int kk = 0; kk < H_ / 32; ++kk) {
        short8 av = *(const short8*)(ap + kk * 32);
        short8 bv = *(const short8*)(bp + kk * 32);
        acc = __builtin_amdgcn_mfma_f32_16x16x32_bf16(av, bv, acc, 0, 0, 0);
      }
    }
    const float biasv = bias_pk[tag * G4H + wg * 16 + arow];

    __syncthreads();  // WAR: previous iter's LDS reads done
#pragma unroll
    for (int r = 0; r < 4; ++r)
      tl[((lane >> 4) * 4 + r) * 16 + arow] = acc[r] + biasv;
    __syncthreads();

    {
      const int u = lane & 3, brow = lane >> 2;
      const float* rp = tl + brow * 16;
      float iv = rp[u], fv = rp[4 + u], gv = rp[8 + u], ov = rp[12 + u];
      float cn = sigm(fv) * c_reg + sigm(iv) * tanhf(gv);
      c_reg = cn;
      float hn = sigm(ov) * tanhf(cn);
      const int b = m0 + brow;
      const int j = wg * 4 + u;
      Anext[b * H_ + j] = f2bf(hn);
      h_f32[b * H_ + j] = hn;
    }
    grid.sync();
  }

  // ================= Phase 2: FFN head =================
  // WG b (<64) handles batch b; thread d handles hidden dim d of D_FF=256.
  if (wg < B_) {
    const int b = wg, d = tid;
    const float* hrow = h_f32 + (size_t)b * H_;
    const float* w1r = W1 + (size_t)d * H_;
    float s = b1[d];
#pragma unroll 4
    for (int k = 0; k < H_; k += 4) {
      f32x4 w = *(const f32x4*)(w1r + k);
      f32x4 h4 = *(const f32x4*)(hrow + k);
      s += w[0] * h4[0] + w[1] * h4[1] + w[2] * h4[2] + w[3] * h4[3];
    }
    s = fmaxf(s, 0.f);
    __shared__ float red[256];
    red[tid] = s * W2[d];
    __syncthreads();
    for (int off = 128; off > 0; off >>= 1) {
      if (tid < off) red[tid] += red[tid + off];
      __syncthreads();
    }
    if (tid == 0) out[b] = 1.f / (1.f + __expf(-(red[0] + b2[0])));
  }
}

extern "C" void kernel_launch(void* const* d_in, const int* in_sizes, int n_in,
                              void* d_out, int out_size, void* d_ws, size_t ws_size,
                              hipStream_t stream) {
  const int* tokens = (const int*)d_in[0];
  const int* tags = (const int*)d_in[1];
  const float* emb_w = (const float*)d_in[2];
  const float* W_ih = (const float*)d_in[3];
  const float* W_hh = (const float*)d_in[4];
  const float* b_ih = (const float*)d_in[5];
  const float* b_hh = (const float*)d_in[6];
  const float* W1 = (const float*)d_in[7];
  const float* b1 = (const float*)d_in[8];
  const float* W2 = (const float*)d_in[9];
  const float* b2 = (const float*)d_in[10];
  float* out = (float*)d_out;

  char* ws = (char*)d_ws;
  short* wih_pk = (short*)(ws + OFF_WIH);
  short* whh_pk = (short*)(ws + OFF_WHH);
  short* x_bf = (short*)(ws + OFF_X);
  float* bias_pk = (float*)(ws + OFF_BIAS);
  short* h_bf = (short*)(ws + OFF_H);
  float* h_f32 = (float*)(ws + OFF_HF);

  void* args[] = {&tokens, &tags, &emb_w, &W_ih, &W_hh, &b_ih, &b_hh,
                  &W1, &b1, &W2, &b2, &out,
                  &wih_pk, &whh_pk, &x_bf, &bias_pk, &h_bf, &h_f32};
  dim3 grid(256), block(256);
  hipLaunchCooperativeKernel(reinterpret_cast<void*>(&lstm_tag_kernel), grid,
                             block, args, 0, stream);
}

// Round 2
// 16435.117 us; speedup vs baseline: 1.3105x; 1.3105x over previous
//
#include <hip/hip_runtime.h>
#include <hip/hip_bf16.h>
#include <hip/hip_cooperative_groups.h>

namespace cg = cooperative_groups;

typedef __attribute__((ext_vector_type(8))) short short8;
typedef __attribute__((ext_vector_type(4))) float f32x4;

static constexpr int E_ = 512, H_ = 1024, S_ = 512, B_ = 64, NT_ = 13;
static constexpr int G4H = 4 * H_;  // 4096

// ---- workspace layout (elements) ----
static constexpr size_t WIH_ELEMS = (size_t)NT_ * G4H * E_;
static constexpr size_t WHH_ELEMS = (size_t)NT_ * G4H * H_;
static constexpr size_t X_ELEMS   = (size_t)S_ * B_ * E_;
static constexpr size_t BIAS_ELEMS = (size_t)NT_ * G4H;
static constexpr size_t HBUF_ELEMS = (size_t)B_ * H_;

static constexpr size_t OFF_WIH  = 0;
static constexpr size_t OFF_WHH  = OFF_WIH + WIH_ELEMS * 2;
static constexpr size_t OFF_X    = OFF_WHH + WHH_ELEMS * 2;
static constexpr size_t OFF_BIAS = OFF_X + X_ELEMS * 2;
static constexpr size_t OFF_H    = OFF_BIAS + BIAS_ELEMS * 4;
// total ~198 MB (known to fit)

static constexpr int BH_STRIDE = 1032;  // 1024 + 8 shorts (16B pad per row)

__device__ inline short f2bf(float x) {
  __hip_bfloat16 h = __float2bfloat16(x);
  return __builtin_bit_cast(short, h);
}
__device__ inline float b2f(short s) {
  unsigned u = ((unsigned)(unsigned short)s) << 16;
  return __builtin_bit_cast(float, u);
}
__device__ inline short8 cvt8(const float* src) {
  f32x4 a = *(const f32x4*)src;
  f32x4 b = *(const f32x4*)(src + 4);
  short8 o;
  o[0] = f2bf(a[0]); o[1] = f2bf(a[1]); o[2] = f2bf(a[2]); o[3] = f2bf(a[3]);
  o[4] = f2bf(b[0]); o[5] = f2bf(b[1]); o[6] = f2bf(b[2]); o[7] = f2bf(b[3]);
  return o;
}
__device__ inline float sigm(float x) { return 1.f / (1.f + __expf(-x)); }

// packed row p (within a tag) -> original row r
__device__ inline int unpack_row(int p) {
  return ((p >> 2) & 3) * H_ + (p >> 4) * 4 + (p & 3);
}

__device__ inline void stage16(const short* g, short* l) {
  __builtin_amdgcn_global_load_lds(
      (const __attribute__((address_space(1))) void*)g,
      (__attribute__((address_space(3))) void*)l, 16, 0, 0);
}

// x-GEMM fragment: acc_x = x[t] @ W_ih[tag]^T for this wave's 16x16 tile
__device__ inline f32x4 xgemm(const short* __restrict__ x_bf,
                              const short* __restrict__ wih_pk,
                              int t, int tag, int wg, int m0, int arow, int kq) {
  const short* ap = x_bf + ((size_t)t * B_ + m0 + arow) * E_ + kq;
  const short* bp = wih_pk + ((size_t)tag * G4H + wg * 16 + arow) * E_ + kq;
  short8 av[16], bv[16];
#pragma unroll
  for (int i = 0; i < 16; ++i) av[i] = *(const short8*)(ap + i * 32);
#pragma unroll
  for (int i = 0; i < 16; ++i) bv[i] = *(const short8*)(bp + i * 32);
  f32x4 a = {0.f, 0.f, 0.f, 0.f};
#pragma unroll
  for (int i = 0; i < 16; ++i)
    a = __builtin_amdgcn_mfma_f32_16x16x32_bf16(av[i], bv[i], a, 0, 0, 0);
  return a;
}

__global__ __launch_bounds__(256, 1) void lstm_tag_kernel(
    const int* __restrict__ tokens, const int* __restrict__ tags,
    const float* __restrict__ emb_w,
    const float* __restrict__ W_ih, const float* __restrict__ W_hh,
    const float* __restrict__ b_ih, const float* __restrict__ b_hh,
    const float* __restrict__ W1, const float* __restrict__ b1,
    const float* __restrict__ W2, const float* __restrict__ b2,
    float* __restrict__ out,
    short* __restrict__ wih_pk, short* __restrict__ whh_pk,
    short* __restrict__ x_bf, float* __restrict__ bias_pk,
    short* __restrict__ h_bf) {
  cg::grid_group grid = cg::this_grid();
  const int tid = threadIdx.x;
  const int wg = blockIdx.x;
  const int lane = tid & 63;
  const int ll = tid >> 6;
  const int gw = wg * 4 + ll;
  const int gtid = wg * 256 + tid;

  __shared__ short lds_bh[16 * BH_STRIDE];  // 33,024 B: W_hh tile (padded rows)
  __shared__ float lds_tile[4 * 256];       // 4,096 B: per-wave gate exchange

  // ================= Phase 0: pre-pass =================
  for (int row = gw; row < NT_ * G4H; row += 1024) {
    int tag = row >> 12, p = row & 4095, r = unpack_row(p);
    const float* src = W_ih + ((size_t)tag * G4H + r) * E_ + lane * 8;
    short* dst = wih_pk + ((size_t)tag * G4H + p) * E_ + lane * 8;
    *(short8*)dst = cvt8(src);
  }
  for (int row = gw; row < NT_ * G4H; row += 1024) {
    int tag = row >> 12, p = row & 4095, r = unpack_row(p);
    const float* src = W_hh + ((size_t)tag * G4H + r) * H_;
    short* dst = whh_pk + ((size_t)tag * G4H + p) * H_;
    *(short8*)(dst + lane * 8) = cvt8(src + lane * 8);
    *(short8*)(dst + 512 + lane * 8) = cvt8(src + 512 + lane * 8);
  }
  for (int idx = gtid; idx < NT_ * G4H; idx += 65536) {
    int tag = idx >> 12;
    int r = unpack_row(idx & 4095);
    bias_pk[idx] = b_ih[tag * G4H + r] + b_hh[tag * G4H + r];
  }
  for (int row = gw; row < S_ * B_; row += 1024) {
    int t = row >> 6, b = row & 63;
    int tok = tokens[b * S_ + t];
    const float* src = emb_w + (size_t)tok * E_ + lane * 8;
    short* dst = x_bf + (size_t)row * E_ + lane * 8;
    *(short8*)dst = cvt8(src);
  }
  ((int*)h_bf)[gtid] = 0;  // zero both h buffers

  grid.sync();

  // ================= Phase 1: recurrence =================
  const int arow = lane & 15;
  const int kq = (lane >> 4) * 8;
  const int m0 = ll * 16;

  int tag = tags[0];
  // Prologue: stage W_hh[tag0] tile into LDS; compute x-contribution for t=0.
  {
    const short* src = whh_pk + ((size_t)tag * G4H + wg * 16) * H_;
#pragma unroll
    for (int rr = 0; rr < 4; ++rr) {
      int r = ll * 4 + rr;
      const short* g = src + r * H_ + lane * 8;
      stage16(g, &lds_bh[r * BH_STRIDE]);
      stage16(g + 512, &lds_bh[r * BH_STRIDE + 512]);
    }
  }
  f32x4 acc_x = xgemm(x_bf, wih_pk, 0, tag, wg, m0, arow, kq);
  __syncthreads();  // staged tile visible to all waves

  float c_reg = 0.f;

  for (int t = 0; t < S_; ++t) {
    const float biasv = bias_pk[tag * G4H + wg * 16 + arow];
    const short* Acur = h_bf + (size_t)(t & 1) * HBUF_ELEMS;
    short* Anext = h_bf + (size_t)((t + 1) & 1) * HBUF_ELEMS;

    // ---- h-GEMM: all 32 A-chunks loaded up-front (pipelined), B from LDS ----
    const short* aph = Acur + (m0 + arow) * H_ + kq;
    const short* bph = &lds_bh[arow * BH_STRIDE + kq];
    short8 ah[32];
#pragma unroll
    for (int i = 0; i < 32; ++i) ah[i] = *(const short8*)(aph + i * 32);
    f32x4 acc = acc_x;
#pragma unroll
    for (int i = 0; i < 32; ++i) {
      short8 bv = *(const short8*)(bph + i * 32);
      acc = __builtin_amdgcn_mfma_f32_16x16x32_bf16(ah[i], bv, acc, 0, 0, 0);
    }

    // ---- gate exchange (wave-local LDS, no block barrier needed) ----
    float* tl = lds_tile + ll * 256;
#pragma unroll
    for (int r = 0; r < 4; ++r)
      tl[((lane >> 4) * 4 + r) * 16 + arow] = acc[r] + biasv;
    __builtin_amdgcn_wave_barrier();
    {
      const int u = lane & 3, brow = lane >> 2;
      const float* rp = tl + brow * 16;
      float iv = rp[u], fv = rp[4 + u], gv = rp[8 + u], ov = rp[12 + u];
      float cn = sigm(fv) * c_reg + sigm(iv) * tanhf(gv);
      c_reg = cn;
      float hn = sigm(ov) * tanhf(cn);
      Anext[(m0 + brow) * H_ + wg * 4 + u] = f2bf(hn);
    }

    __syncthreads();  // all waves done reading lds_bh; safe to overwrite

    if (t < S_ - 1) {
      const int tagn = tags[t + 1];
      // shadow x-GEMM for t+1 (independent of h -> off the critical path)
      acc_x = xgemm(x_bf, wih_pk, t + 1, tagn, wg, m0, arow, kq);
      // prefetch W_hh[tag_{t+1}] tile; DMA overlaps the grid barrier wait
      const short* src = whh_pk + ((size_t)tagn * G4H + wg * 16) * H_;
#pragma unroll
      for (int rr = 0; rr < 4; ++rr) {
        int r = ll * 4 + rr;
        const short* g = src + r * H_ + lane * 8;
        stage16(g, &lds_bh[r * BH_STRIDE]);
        stage16(g + 512, &lds_bh[r * BH_STRIDE + 512]);
      }
      tag = tagn;
    }
    grid.sync();  // publish h_t; drains prefetch DMA before next iteration
  }

  // ================= Phase 2: FFN head =================
  if (wg < B_) {
    const int b = wg, d = tid;
    const short* hrow = h_bf + (size_t)((S_)&1) * HBUF_ELEMS + (size_t)b * H_;
    const float* w1r = W1 + (size_t)d * H_;
    float s = b1[d];
#pragma unroll 4
    for (int k = 0; k < H_; k += 8) {
      short8 hv = *(const short8*)(hrow + k);
      f32x4 w0 = *(const f32x4*)(w1r + k);
      f32x4 w1v = *(const f32x4*)(w1r + k + 4);
      s += w0[0] * b2f(hv[0]) + w0[1] * b2f(hv[1]) + w0[2] * b2f(hv[2]) +
           w0[3] * b2f(hv[3]) + w1v[0] * b2f(hv[4]) + w1v[1] * b2f(hv[5]) +
           w1v[2] * b2f(hv[6]) + w1v[3] * b2f(hv[7]);
    }
    s = fmaxf(s, 0.f);
    __shared__ float red[256];
    red[tid] = s * W2[d];
    __syncthreads();
    for (int off = 128; off > 0; off >>= 1) {
      if (tid < off) red[tid] += red[tid + off];
      __syncthreads();
    }
    if (tid == 0) out[b] = 1.f / (1.f + __expf(-(red[0] + b2[0])));
  }
}

extern "C" void kernel_launch(void* const* d_in, const int* in_sizes, int n_in,
                              void* d_out, int out_size, void* d_ws, size_t ws_size,
                              hipStream_t stream) {
  const int* tokens = (const int*)d_in[0];
  const int* tags = (const int*)d_in[1];
  const float* emb_w = (const float*)d_in[2];
  const float* W_ih = (const float*)d_in[3];
  const float* W_hh = (const float*)d_in[4];
  const float* b_ih = (const float*)d_in[5];
  const float* b_hh = (const float*)d_in[6];
  const float* W1 = (const float*)d_in[7];
  const float* b1 = (const float*)d_in[8];
  const float* W2 = (const float*)d_in[9];
  const float* b2 = (const float*)d_in[10];
  float* out = (float*)d_out;

  char* ws = (char*)d_ws;
  short* wih_pk = (short*)(ws + OFF_WIH);
  short* whh_pk = (short*)(ws + OFF_WHH);
  short* x_bf = (short*)(ws + OFF_X);
  float* bias_pk = (float*)(ws + OFF_BIAS);
  short* h_bf = (short*)(ws + OFF_H);

  void* args[] = {&tokens, &tags, &emb_w, &W_ih, &W_hh, &b_ih, &b_hh,
                  &W1, &b1, &W2, &b2, &out,
                  &wih_pk, &whh_pk, &x_bf, &bias_pk, &h_bf};
  dim3 grid(256), block(256);
  hipLaunchCooperativeKernel(reinterpret_cast<void*>(&lstm_tag_kernel), grid,
                             block, args, 0, stream);
}

// Round 3
// 7349.239 us; speedup vs baseline: 2.9308x; 2.2363x over previous
//
#include <hip/hip_runtime.h>
#include <hip/hip_bf16.h>
#include <hip/hip_cooperative_groups.h>

namespace cg = cooperative_groups;

typedef __attribute__((ext_vector_type(8))) short short8;
typedef __attribute__((ext_vector_type(4))) float f32x4;
typedef unsigned long long ull;

static constexpr int E_ = 512, H_ = 1024, S_ = 512, B_ = 64, NT_ = 13;
static constexpr int G4H = 4 * H_;  // 4096

// ---- workspace layout ----
static constexpr size_t WIH_ELEMS = (size_t)NT_ * G4H * E_;
static constexpr size_t WHH_ELEMS = (size_t)NT_ * G4H * H_;
static constexpr size_t X_ELEMS   = (size_t)S_ * B_ * E_;
static constexpr size_t BIAS_ELEMS = (size_t)NT_ * G4H;
static constexpr size_t HBUF_ELEMS = (size_t)B_ * H_;

static constexpr size_t OFF_WIH  = 0;
static constexpr size_t OFF_WHH  = OFF_WIH + WIH_ELEMS * 2;
static constexpr size_t OFF_X    = OFF_WHH + WHH_ELEMS * 2;
static constexpr size_t OFF_BIAS = OFF_X + X_ELEMS * 2;
static constexpr size_t OFF_H    = OFF_BIAS + BIAS_ELEMS * 4;
static constexpr size_t OFF_BAR  = OFF_H + 2 * HBUF_ELEMS * 2;  // one uint

static constexpr int BH_STRIDE = 1032;  // shorts; 16B pad per row

__device__ inline short f2bf(float x) {
  __hip_bfloat16 h = __float2bfloat16(x);
  return __builtin_bit_cast(short, h);
}
__device__ inline float b2f(short s) {
  unsigned u = ((unsigned)(unsigned short)s) << 16;
  return __builtin_bit_cast(float, u);
}
__device__ inline short8 cvt8(const float* src) {
  f32x4 a = *(const f32x4*)src;
  f32x4 b = *(const f32x4*)(src + 4);
  short8 o;
  o[0] = f2bf(a[0]); o[1] = f2bf(a[1]); o[2] = f2bf(a[2]); o[3] = f2bf(a[3]);
  o[4] = f2bf(b[0]); o[5] = f2bf(b[1]); o[6] = f2bf(b[2]); o[7] = f2bf(b[3]);
  return o;
}
__device__ inline float sigm(float x) { return 1.f / (1.f + __expf(-x)); }

__device__ inline int unpack_row(int p) {
  return ((p >> 2) & 3) * H_ + (p >> 4) * 4 + (p & 3);
}

__device__ inline void stage16(const short* g, short* l) {
  __builtin_amdgcn_global_load_lds(
      (const __attribute__((address_space(1))) void*)g,
      (__attribute__((address_space(3))) void*)l, 16, 0, 0);
}

__device__ inline f32x4 xgemm(const short* __restrict__ x_bf,
                              const short* __restrict__ wih_pk,
                              int t, int tag, int wg, int m0, int arow, int kq) {
  const short* ap = x_bf + ((size_t)t * B_ + m0 + arow) * E_ + kq;
  const short* bp = wih_pk + ((size_t)tag * G4H + wg * 16 + arow) * E_ + kq;
  short8 av[16], bv[16];
#pragma unroll
  for (int i = 0; i < 16; ++i) av[i] = *(const short8*)(ap + i * 32);
#pragma unroll
  for (int i = 0; i < 16; ++i) bv[i] = *(const short8*)(bp + i * 32);
  f32x4 a = {0.f, 0.f, 0.f, 0.f};
#pragma unroll
  for (int i = 0; i < 16; ++i)
    a = __builtin_amdgcn_mfma_f32_16x16x32_bf16(av[i], bv[i], a, 0, 0, 0);
  return a;
}

__global__ __launch_bounds__(256, 1) void lstm_tag_kernel(
    const int* __restrict__ tokens, const int* __restrict__ tags,
    const float* __restrict__ emb_w,
    const float* __restrict__ W_ih, const float* __restrict__ W_hh,
    const float* __restrict__ b_ih, const float* __restrict__ b_hh,
    const float* __restrict__ W1, const float* __restrict__ b1,
    const float* __restrict__ W2, const float* __restrict__ b2,
    float* __restrict__ out,
    short* __restrict__ wih_pk, short* __restrict__ whh_pk,
    short* __restrict__ x_bf, float* __restrict__ bias_pk,
    short* __restrict__ h_bf, unsigned* __restrict__ bar) {
  cg::grid_group grid = cg::this_grid();
  const int tid = threadIdx.x;
  const int wg = blockIdx.x;
  const int lane = tid & 63;
  const int ll = tid >> 6;
  const int gw = wg * 4 + ll;
  const int gtid = wg * 256 + tid;

  __shared__ short lds_bh[16 * BH_STRIDE];  // W_hh tile (padded rows)
  __shared__ float lds_tile[4 * 256];       // gate exchange
  __shared__ ull lds_hst_q[32];             // packed h staging (256 shorts)
  short* lds_hst = (short*)lds_hst_q;

  // ================= Phase 0: pre-pass =================
  for (int row = gw; row < NT_ * G4H; row += 1024) {
    int tag = row >> 12, p = row & 4095, r = unpack_row(p);
    const float* src = W_ih + ((size_t)tag * G4H + r) * E_ + lane * 8;
    short* dst = wih_pk + ((size_t)tag * G4H + p) * E_ + lane * 8;
    *(short8*)dst = cvt8(src);
  }
  for (int row = gw; row < NT_ * G4H; row += 1024) {
    int tag = row >> 12, p = row & 4095, r = unpack_row(p);
    const float* src = W_hh + ((size_t)tag * G4H + r) * H_;
    short* dst = whh_pk + ((size_t)tag * G4H + p) * H_;
    *(short8*)(dst + lane * 8) = cvt8(src + lane * 8);
    *(short8*)(dst + 512 + lane * 8) = cvt8(src + 512 + lane * 8);
  }
  for (int idx = gtid; idx < NT_ * G4H; idx += 65536) {
    int tag = idx >> 12;
    int r = unpack_row(idx & 4095);
    bias_pk[idx] = b_ih[tag * G4H + r] + b_hh[tag * G4H + r];
  }
  for (int row = gw; row < S_ * B_; row += 1024) {
    int t = row >> 6, b = row & 63;
    int tok = tokens[b * S_ + t];
    const float* src = emb_w + (size_t)tok * E_ + lane * 8;
    short* dst = x_bf + (size_t)row * E_ + lane * 8;
    *(short8*)dst = cvt8(src);
  }
  ((int*)h_bf)[gtid] = 0;  // zero both h buffers
  if (gtid == 0) *bar = 0u;

  grid.sync();  // full fence: packed data + zeroed h/bar visible everywhere

  // ================= Phase 1: recurrence =================
  const int arow = lane & 15;
  const int kq = (lane >> 4) * 8;
  const int m0 = ll * 16;

  int tag = tags[0];
  {
    const short* src = whh_pk + ((size_t)tag * G4H + wg * 16) * H_;
#pragma unroll
    for (int rr = 0; rr < 4; ++rr) {
      int r = ll * 4 + rr;
      const short* g = src + r * H_ + lane * 8;
      stage16(g, &lds_bh[r * BH_STRIDE]);
      stage16(g + 512, &lds_bh[r * BH_STRIDE + 512]);
    }
  }
  f32x4 acc_x = xgemm(x_bf, wih_pk, 0, tag, wg, m0, arow, kq);
  asm volatile("s_waitcnt vmcnt(0)" ::: "memory");  // DMA drained
  __syncthreads();

  float c_reg = 0.f;

  for (int t = 0; t < S_; ++t) {
    const short* Acur = h_bf + (size_t)(t & 1) * HBUF_ELEMS;
    short* Anext = h_bf + (size_t)((t + 1) & 1) * HBUF_ELEMS;

    // ---- h A-tile: coherent (agent-scope) loads from the coherence point ----
    ull* ab = (ull*)(Acur + (size_t)(m0 + arow) * H_);
    const int ib = kq >> 2;
    short8 ah[32];
#pragma unroll
    for (int i = 0; i < 32; ++i) {
      ull lo = __hip_atomic_load(ab + ib + i * 8, __ATOMIC_RELAXED,
                                 __HIP_MEMORY_SCOPE_AGENT);
      ull hi = __hip_atomic_load(ab + ib + i * 8 + 1, __ATOMIC_RELAXED,
                                 __HIP_MEMORY_SCOPE_AGENT);
      union { ull q[2]; short8 s; } u;
      u.q[0] = lo; u.q[1] = hi;
      ah[i] = u.s;
    }

    // ---- h-GEMM, 2 independent accumulator chains ----
    const short* bph = &lds_bh[arow * BH_STRIDE + kq];
    f32x4 acc0 = acc_x;
    f32x4 acc1 = {0.f, 0.f, 0.f, 0.f};
#pragma unroll
    for (int i = 0; i < 16; ++i) {
      short8 b0 = *(const short8*)(bph + (2 * i) * 32);
      short8 b1v = *(const short8*)(bph + (2 * i + 1) * 32);
      acc0 = __builtin_amdgcn_mfma_f32_16x16x32_bf16(ah[2 * i], b0, acc0, 0, 0, 0);
      acc1 = __builtin_amdgcn_mfma_f32_16x16x32_bf16(ah[2 * i + 1], b1v, acc1, 0, 0, 0);
    }
    const float biasv = bias_pk[tag * G4H + wg * 16 + arow];

    // ---- gate exchange (wave-local) ----
    float* tl = lds_tile + ll * 256;
#pragma unroll
    for (int r = 0; r < 4; ++r)
      tl[((lane >> 4) * 4 + r) * 16 + arow] = acc0[r] + acc1[r] + biasv;
    __builtin_amdgcn_wave_barrier();
    {
      const int u = lane & 3, brow = lane >> 2;
      const float* rp = tl + brow * 16;
      float iv = rp[u], fv = rp[4 + u], gv = rp[8 + u], ov = rp[12 + u];
      float cn = sigm(fv) * c_reg + sigm(iv) * tanhf(gv);
      c_reg = cn;
      float hn = sigm(ov) * tanhf(cn);
      lds_hst[(m0 + brow) * 4 + u] = f2bf(hn);
    }

    __syncthreads();  // lds_hst complete; all waves done reading lds_bh

    // ---- wave 0: publish h (coherent stores), then arrive ----
    if (ll == 0) {
      ull v = *(const ull*)&lds_hst[lane * 4];
      __hip_atomic_store((ull*)(Anext + (size_t)lane * H_ + wg * 4), v,
                         __ATOMIC_RELAXED, __HIP_MEMORY_SCOPE_AGENT);
      asm volatile("s_waitcnt vmcnt(0)" ::: "memory");  // stores at coherence pt
      if (lane == 0)
        __hip_atomic_fetch_add(bar, 1u, __ATOMIC_RELAXED,
                               __HIP_MEMORY_SCOPE_AGENT);
    }

    // ---- shadow work for t+1 (overlaps other WGs' compute + our spin) ----
    if (t < S_ - 1) {
      const int tagn = tags[t + 1];
      acc_x = xgemm(x_bf, wih_pk, t + 1, tagn, wg, m0, arow, kq);
      const short* src = whh_pk + ((size_t)tagn * G4H + wg * 16) * H_;
#pragma unroll
      for (int rr = 0; rr < 4; ++rr) {
        int r = ll * 4 + rr;
        const short* g = src + r * H_ + lane * 8;
        stage16(g, &lds_bh[r * BH_STRIDE]);
        stage16(g + 512, &lds_bh[r * BH_STRIDE + 512]);
      }
      tag = tagn;
    }
    asm volatile("s_waitcnt vmcnt(0)" ::: "memory");  // own DMA drained

    // ---- barrier wait ----
    if (tid == 0) {
      const unsigned target = 256u * (unsigned)(t + 1);
      while (__hip_atomic_load(bar, __ATOMIC_RELAXED,
                               __HIP_MEMORY_SCOPE_AGENT) < target)
        __builtin_amdgcn_s_sleep(8);
    }
    __syncthreads();
  }

  grid.sync();  // full fence: final h coherent for plain loads below

  // ================= Phase 2: FFN head =================
  if (wg < B_) {
    const int b = wg, d = tid;
    const short* hrow = h_bf + (size_t)(S_ & 1) * HBUF_ELEMS + (size_t)b * H_;
    const float* w1r = W1 + (size_t)d * H_;
    float s = b1[d];
#pragma unroll 4
    for (int k = 0; k < H_; k += 8) {
      short8 hv = *(const short8*)(hrow + k);
      f32x4 w0 = *(const f32x4*)(w1r + k);
      f32x4 w1v = *(const f32x4*)(w1r + k + 4);
      s += w0[0] * b2f(hv[0]) + w0[1] * b2f(hv[1]) + w0[2] * b2f(hv[2]) +
           w0[3] * b2f(hv[3]) + w1v[0] * b2f(hv[4]) + w1v[1] * b2f(hv[5]) +
           w1v[2] * b2f(hv[6]) + w1v[3] * b2f(hv[7]);
    }
    s = fmaxf(s, 0.f);
    __shared__ float red[256];
    red[tid] = s * W2[d];
    __syncthreads();
    for (int off = 128; off > 0; off >>= 1) {
      if (tid < off) red[tid] += red[tid + off];
      __syncthreads();
    }
    if (tid == 0) out[b] = 1.f / (1.f + __expf(-(red[0] + b2[0])));
  }
}

extern "C" void kernel_launch(void* const* d_in, const int* in_sizes, int n_in,
                              void* d_out, int out_size, void* d_ws, size_t ws_size,
                              hipStream_t stream) {
  const int* tokens = (const int*)d_in[0];
  const int* tags = (const int*)d_in[1];
  const float* emb_w = (const float*)d_in[2];
  const float* W_ih = (const float*)d_in[3];
  const float* W_hh = (const float*)d_in[4];
  const float* b_ih = (const float*)d_in[5];
  const float* b_hh = (const float*)d_in[6];
  const float* W1 = (const float*)d_in[7];
  const float* b1 = (const float*)d_in[8];
  const float* W2 = (const float*)d_in[9];
  const float* b2 = (const float*)d_in[10];
  float* out = (float*)d_out;

  char* ws = (char*)d_ws;
  short* wih_pk = (short*)(ws + OFF_WIH);
  short* whh_pk = (short*)(ws + OFF_WHH);
  short* x_bf = (short*)(ws + OFF_X);
  float* bias_pk = (float*)(ws + OFF_BIAS);
  short* h_bf = (short*)(ws + OFF_H);
  unsigned* bar = (unsigned*)(ws + OFF_BAR);

  void* args[] = {&tokens, &tags, &emb_w, &W_ih, &W_hh, &b_ih, &b_hh,
                  &W1, &b1, &W2, &b2, &out,
                  &wih_pk, &whh_pk, &x_bf, &bias_pk, &h_bf, &bar};
  dim3 grid(256), block(256);
  hipLaunchCooperativeKernel(reinterpret_cast<void*>(&lstm_tag_kernel), grid,
                             block, args, 0, stream);
}